// Round 3
// baseline (49.792 us; speedup 1.0000x reference)
//
#include <hip/hip_runtime.h>

#define BATCH 64
#define IMH 256
#define IMW 256
#define CIN 512
#define NH 128
#define BPB 8                       // blocks per batch
#define ROWS_PB (IMH / BPB)         // 32 rows per block
#define NTILES (ROWS_PB / 4)        // 8 tiles of 4 rows x 256 cols

// One fused kernel: each block (256 thr) redundantly computes the 10-wide MLP
// head for its batch (weights stream from L2; 8x redundancy is ~4 us chip-wide),
// then smooth-max-pools its 32 image rows. Single dispatch -> minimal replay
// overhead; no cross-block dependencies.
__global__ __launch_bounds__(256) void fused_kernel(
        const float* __restrict__ x,
        const float* __restrict__ features,
        const float* __restrict__ W0, const float* __restrict__ b0,
        const float* __restrict__ W1, const float* __restrict__ b1,
        const float* __restrict__ W2, const float* __restrict__ b2,
        float* __restrict__ out) {
    const int t     = threadIdx.x;    // 0..255
    const int wave  = t >> 6;         // 0..3
    const int lane  = t & 63;
    const int batch = blockIdx.x >> 3;
    const int bgrp  = blockIdx.x & 7;

    __shared__ float f[CIN];
    __shared__ float h0[NH];
    __shared__ float h1[NH];
    __shared__ float akl[10];

    // ---------------- phase A: MLP (redundant per block) ----------------
    f[t]       = features[batch * CIN + t];
    f[t + 256] = features[batch * CIN + t + 256];
    __syncthreads();

    // layer 0: 32 rows per wave, lanes stride the 512-dim, shuffle-reduce
    #pragma unroll 2
    for (int r0 = 0; r0 < ROWS_PB; ++r0) {
        const int r = wave * 32 + r0;
        const float* w = W0 + r * CIN;
        float acc = 0.f;
        #pragma unroll
        for (int k = 0; k < CIN / 64; ++k)
            acc = fmaf(w[lane + 64 * k], f[lane + 64 * k], acc);
        #pragma unroll
        for (int off = 32; off > 0; off >>= 1)
            acc += __shfl_down(acc, off);
        if (lane == 0) h0[r] = fmaxf(acc + b0[r], 0.f);
    }
    __syncthreads();

    // layer 1: 32 rows per wave, dot over 128
    #pragma unroll 2
    for (int r0 = 0; r0 < 32; ++r0) {
        const int r = wave * 32 + r0;
        const float* w = W1 + r * NH;
        float acc = 0.f;
        #pragma unroll
        for (int k = 0; k < NH / 64; ++k)
            acc = fmaf(w[lane + 64 * k], h0[lane + 64 * k], acc);
        #pragma unroll
        for (int off = 32; off > 0; off >>= 1)
            acc += __shfl_down(acc, off);
        if (lane == 0) h1[r] = fmaxf(acc + b1[r], 0.f);
    }
    __syncthreads();

    // layer 2: 10 outputs spread over 4 waves
    for (int r = wave; r < 10; r += 4) {
        const float* w = W2 + r * NH;
        float acc = 0.f;
        #pragma unroll
        for (int k = 0; k < NH / 64; ++k)
            acc = fmaf(w[lane + 64 * k], h1[lane + 64 * k], acc);
        #pragma unroll
        for (int off = 32; off > 0; off >>= 1)
            acc += __shfl_down(acc, off);
        if (lane == 0) {
            float beta = acc + b2[r];
            if (r == 0) {
                akl[0] = beta;                         // alpha
            } else {
                beta += (r == 5) ? 5.f : -5.f;         // identity bias (center +5)
                akl[r] = 1.f / (1.f + __expf(-beta));  // sigmoid
            }
        }
    }
    __syncthreads();

    const float alpha = akl[0];
    float kern[9];
    #pragma unroll
    for (int i = 0; i < 9; ++i) kern[i] = akl[1 + i];

    // ---------------- phase B: smooth-max pool 32 rows ----------------
    const float* xb = x + ((size_t)batch << 16);
    float* ob       = out + ((size_t)batch << 16);
    const int c0    = (t & 63) << 2;        // 0,4,...,252

    #pragma unroll 2
    for (int tile = 0; tile < NTILES; ++tile) {
        const int row = bgrp * ROWS_PB + tile * 4 + (t >> 6);

        float num[4] = {0.f, 0.f, 0.f, 0.f};
        float den[4] = {0.f, 0.f, 0.f, 0.f};

        #pragma unroll
        for (int dy = -1; dy <= 1; ++dy) {
            const int rr = row + dy;
            float p[6];
            if ((unsigned)rr < (unsigned)IMH) {
                const float* xr = xb + rr * IMW;
                const float4 v = *reinterpret_cast<const float4*>(xr + c0);
                p[0] = (c0 == 0)       ? 0.f : xr[c0 - 1];
                p[1] = v.x; p[2] = v.y; p[3] = v.z; p[4] = v.w;
                p[5] = (c0 == IMW - 4) ? 0.f : xr[c0 + 4];
            } else {
                #pragma unroll
                for (int j = 0; j < 6; ++j) p[j] = 0.f;
            }
            float e[6];
            #pragma unroll
            for (int j = 0; j < 6; ++j) e[j] = __expf(alpha * p[j]);
            const int kr = (dy + 1) * 3;
            #pragma unroll
            for (int i = 0; i < 4; ++i) {
                #pragma unroll
                for (int dx = 0; dx < 3; ++dx) {
                    const float wt = e[i + dx] * kern[kr + dx];
                    num[i] = fmaf(p[i + dx], wt, num[i]);
                    den[i] += wt;
                }
            }
        }

        float4 o;
        o.x = num[0] * __builtin_amdgcn_rcpf(den[0]);
        o.y = num[1] * __builtin_amdgcn_rcpf(den[1]);
        o.z = num[2] * __builtin_amdgcn_rcpf(den[2]);
        o.w = num[3] * __builtin_amdgcn_rcpf(den[3]);
        *reinterpret_cast<float4*>(ob + row * IMW + c0) = o;
    }
}

extern "C" void kernel_launch(void* const* d_in, const int* in_sizes, int n_in,
                              void* d_out, int out_size, void* d_ws, size_t ws_size,
                              hipStream_t stream) {
    const float* x        = (const float*)d_in[0];
    const float* features = (const float*)d_in[1];
    const float* W0       = (const float*)d_in[2];
    const float* b0       = (const float*)d_in[3];
    const float* W1       = (const float*)d_in[4];
    const float* b1       = (const float*)d_in[5];
    const float* W2       = (const float*)d_in[6];
    const float* b2       = (const float*)d_in[7];
    float* out = (float*)d_out;

    fused_kernel<<<BATCH * BPB, 256, 0, stream>>>(
        x, features, W0, b0, W1, b1, W2, b2, out);
}

// Round 4
// 30.269 us; speedup vs baseline: 1.6450x; 1.6450x over previous
//
#include <hip/hip_runtime.h>

#define BATCH 64
#define IMH 256
#define IMW 256
#define CIN 512
#define NH 128

// Kernel 1: per-batch MLP -> alpha + 9 sigmoid kernel weights.
// 64 blocks x 1024 threads (16 waves). Each wave owns 8 rows per layer;
// lanes stride the dot dimension with float4/float2 coalesced loads,
// shuffle-tree reduce. Minimizes the serial dependent-chain depth that
// made round 3 latency-bound.
__global__ __launch_bounds__(1024) void mlp_kernel(
        const float* __restrict__ features,
        const float* __restrict__ W0, const float* __restrict__ b0,
        const float* __restrict__ W1, const float* __restrict__ b1,
        const float* __restrict__ W2, const float* __restrict__ b2,
        float* __restrict__ ak /* [BATCH][10] */) {
    const int b    = blockIdx.x;
    const int t    = threadIdx.x;   // 0..1023
    const int wave = t >> 6;        // 0..15
    const int lane = t & 63;

    __shared__ float f[CIN];
    __shared__ float h0[NH];
    __shared__ float h1[NH];

    if (t < CIN) f[t] = features[b * CIN + t];
    __syncthreads();

    // ---- layer 0: 8 rows per wave, dot over 512 via float4 ----
    const float4* f4 = reinterpret_cast<const float4*>(f);
    #pragma unroll
    for (int r0 = 0; r0 < 8; ++r0) {
        const int r = wave * 8 + r0;
        const float4* w4 = reinterpret_cast<const float4*>(W0 + r * CIN);
        float acc = 0.f;
        #pragma unroll
        for (int k = 0; k < 2; ++k) {
            const float4 wv = w4[lane + 64 * k];
            const float4 fv = f4[lane + 64 * k];
            acc = fmaf(wv.x, fv.x, acc);
            acc = fmaf(wv.y, fv.y, acc);
            acc = fmaf(wv.z, fv.z, acc);
            acc = fmaf(wv.w, fv.w, acc);
        }
        #pragma unroll
        for (int off = 32; off > 0; off >>= 1)
            acc += __shfl_down(acc, off);
        if (lane == 0) h0[r] = fmaxf(acc + b0[r], 0.f);
    }
    __syncthreads();

    // ---- layer 1: 8 rows per wave, dot over 128 via float2 ----
    const float2* h02 = reinterpret_cast<const float2*>(h0);
    #pragma unroll
    for (int r0 = 0; r0 < 8; ++r0) {
        const int r = wave * 8 + r0;
        const float2 wv = reinterpret_cast<const float2*>(W1 + r * NH)[lane];
        const float2 hv = h02[lane];
        float acc = fmaf(wv.y, hv.y, wv.x * hv.x);
        #pragma unroll
        for (int off = 32; off > 0; off >>= 1)
            acc += __shfl_down(acc, off);
        if (lane == 0) h1[r] = fmaxf(acc + b1[r], 0.f);
    }
    __syncthreads();

    // ---- head: 10 outputs, one per wave ----
    if (wave < 10) {
        const int r = wave;
        const float2 wv = reinterpret_cast<const float2*>(W2 + r * NH)[lane];
        const float2 hv = reinterpret_cast<const float2*>(h1)[lane];
        float acc = fmaf(wv.y, hv.y, wv.x * hv.x);
        #pragma unroll
        for (int off = 32; off > 0; off >>= 1)
            acc += __shfl_down(acc, off);
        if (lane == 0) {
            float beta = acc + b2[r];
            float outv;
            if (r == 0) {
                outv = beta;                        // alpha
            } else {
                beta += (r == 5) ? 5.f : -5.f;      // identity bias (center +5)
                outv = 1.f / (1.f + __expf(-beta)); // sigmoid
            }
            ak[b * 10 + r] = outv;
        }
    }
}

// Kernel 2: 3x3 smooth-max pooling, 8 px/thread via 2x float4.
// grid = (32, 64): block = 256 thr = 8 rows x 32 col-segments of 8 px.
// 2048 blocks x 4 waves = 8192 waves = 32 waves/CU -> full occupancy.
// Per input row: 10 loads, 10 exps shared by 8 output px (3.75 exps/px).
// OOB taps: p=0 -> e=1, wt=kern, matching the reference's zero padding.
__global__ __launch_bounds__(256) void smoothmax_kernel(
        const float* __restrict__ x,
        const float* __restrict__ ak,
        float* __restrict__ out) {
    const int t   = threadIdx.x;
    const int b   = blockIdx.y;
    const int row = (blockIdx.x << 3) + (t >> 5);   // 0..255
    const int c0  = (t & 31) << 3;                  // 0,8,...,248

    const float* akb = ak + b * 10;
    const float alpha = akb[0];
    float kern[9];
    #pragma unroll
    for (int i = 0; i < 9; ++i) kern[i] = akb[1 + i];

    const float* xb = x + ((size_t)b << 16);

    float num[8], den[8];
    #pragma unroll
    for (int i = 0; i < 8; ++i) { num[i] = 0.f; den[i] = 0.f; }

    #pragma unroll
    for (int dy = -1; dy <= 1; ++dy) {
        const int rr = row + dy;
        float p[10];
        if ((unsigned)rr < (unsigned)IMH) {
            const float* xr = xb + rr * IMW;
            const float4 v0 = *reinterpret_cast<const float4*>(xr + c0);
            const float4 v1 = *reinterpret_cast<const float4*>(xr + c0 + 4);
            p[0] = (c0 == 0)       ? 0.f : xr[c0 - 1];
            p[1] = v0.x; p[2] = v0.y; p[3] = v0.z; p[4] = v0.w;
            p[5] = v1.x; p[6] = v1.y; p[7] = v1.z; p[8] = v1.w;
            p[9] = (c0 == IMW - 8) ? 0.f : xr[c0 + 8];
        } else {
            #pragma unroll
            for (int j = 0; j < 10; ++j) p[j] = 0.f;
        }
        float e[10];
        #pragma unroll
        for (int j = 0; j < 10; ++j) e[j] = __expf(alpha * p[j]);
        const int kr = (dy + 1) * 3;
        #pragma unroll
        for (int i = 0; i < 8; ++i) {
            #pragma unroll
            for (int dx = 0; dx < 3; ++dx) {
                const float wt = e[i + dx] * kern[kr + dx];
                num[i] = fmaf(p[i + dx], wt, num[i]);
                den[i] += wt;
            }
        }
    }

    float* ob = out + ((size_t)b << 16) + row * IMW + c0;
    float4 o0, o1;
    o0.x = num[0] * __builtin_amdgcn_rcpf(den[0]);
    o0.y = num[1] * __builtin_amdgcn_rcpf(den[1]);
    o0.z = num[2] * __builtin_amdgcn_rcpf(den[2]);
    o0.w = num[3] * __builtin_amdgcn_rcpf(den[3]);
    o1.x = num[4] * __builtin_amdgcn_rcpf(den[4]);
    o1.y = num[5] * __builtin_amdgcn_rcpf(den[5]);
    o1.z = num[6] * __builtin_amdgcn_rcpf(den[6]);
    o1.w = num[7] * __builtin_amdgcn_rcpf(den[7]);
    *reinterpret_cast<float4*>(ob)     = o0;
    *reinterpret_cast<float4*>(ob + 4) = o1;
}

extern "C" void kernel_launch(void* const* d_in, const int* in_sizes, int n_in,
                              void* d_out, int out_size, void* d_ws, size_t ws_size,
                              hipStream_t stream) {
    const float* x        = (const float*)d_in[0];
    const float* features = (const float*)d_in[1];
    const float* W0       = (const float*)d_in[2];
    const float* b0       = (const float*)d_in[3];
    const float* W1       = (const float*)d_in[4];
    const float* b1       = (const float*)d_in[5];
    const float* W2       = (const float*)d_in[6];
    const float* b2       = (const float*)d_in[7];
    float* out = (float*)d_out;
    float* ak  = (float*)d_ws;  // BATCH*10 floats

    mlp_kernel<<<BATCH, 1024, 0, stream>>>(features, W0, b0, W1, b1, W2, b2, ak);
    smoothmax_kernel<<<dim3(32, BATCH), 256, 0, stream>>>(x, ak, out);
}

// Round 5
// 29.017 us; speedup vs baseline: 1.7159x; 1.0431x over previous
//
#include <hip/hip_runtime.h>

#define BATCH 64
#define IMH 256
#define IMW 256
#define CIN 512
#define NH 128

// Kernel 1: per-batch MLP -> alpha + 9 sigmoid kernel weights.
// 64 blocks x 1024 threads (16 waves); wave-per-row coalesced dots with
// shuffle-tree reduction. (Unchanged from round 4 — near its latency floor.)
__global__ __launch_bounds__(1024) void mlp_kernel(
        const float* __restrict__ features,
        const float* __restrict__ W0, const float* __restrict__ b0,
        const float* __restrict__ W1, const float* __restrict__ b1,
        const float* __restrict__ W2, const float* __restrict__ b2,
        float* __restrict__ ak /* [BATCH][10] */) {
    const int b    = blockIdx.x;
    const int t    = threadIdx.x;   // 0..1023
    const int wave = t >> 6;        // 0..15
    const int lane = t & 63;

    __shared__ float f[CIN];
    __shared__ float h0[NH];
    __shared__ float h1[NH];

    if (t < CIN) f[t] = features[b * CIN + t];
    __syncthreads();

    // ---- layer 0: 8 rows per wave, dot over 512 via float4 ----
    const float4* f4 = reinterpret_cast<const float4*>(f);
    #pragma unroll
    for (int r0 = 0; r0 < 8; ++r0) {
        const int r = wave * 8 + r0;
        const float4* w4 = reinterpret_cast<const float4*>(W0 + r * CIN);
        float acc = 0.f;
        #pragma unroll
        for (int k = 0; k < 2; ++k) {
            const float4 wv = w4[lane + 64 * k];
            const float4 fv = f4[lane + 64 * k];
            acc = fmaf(wv.x, fv.x, acc);
            acc = fmaf(wv.y, fv.y, acc);
            acc = fmaf(wv.z, fv.z, acc);
            acc = fmaf(wv.w, fv.w, acc);
        }
        #pragma unroll
        for (int off = 32; off > 0; off >>= 1)
            acc += __shfl_down(acc, off);
        if (lane == 0) h0[r] = fmaxf(acc + b0[r], 0.f);
    }
    __syncthreads();

    // ---- layer 1: 8 rows per wave, dot over 128 via float2 ----
    const float2* h02 = reinterpret_cast<const float2*>(h0);
    #pragma unroll
    for (int r0 = 0; r0 < 8; ++r0) {
        const int r = wave * 8 + r0;
        const float2 wv = reinterpret_cast<const float2*>(W1 + r * NH)[lane];
        const float2 hv = h02[lane];
        float acc = fmaf(wv.y, hv.y, wv.x * hv.x);
        #pragma unroll
        for (int off = 32; off > 0; off >>= 1)
            acc += __shfl_down(acc, off);
        if (lane == 0) h1[r] = fmaxf(acc + b1[r], 0.f);
    }
    __syncthreads();

    // ---- head: 10 outputs, one per wave ----
    if (wave < 10) {
        const int r = wave;
        const float2 wv = reinterpret_cast<const float2*>(W2 + r * NH)[lane];
        const float2 hv = reinterpret_cast<const float2*>(h1)[lane];
        float acc = fmaf(wv.y, hv.y, wv.x * hv.x);
        #pragma unroll
        for (int off = 32; off > 0; off >>= 1)
            acc += __shfl_down(acc, off);
        if (lane == 0) {
            float beta = acc + b2[r];
            float outv;
            if (r == 0) {
                outv = beta;                        // alpha
            } else {
                beta += (r == 5) ? 5.f : -5.f;      // identity bias (center +5)
                outv = 1.f / (1.f + __expf(-beta)); // sigmoid
            }
            ak[b * 10 + r] = outv;
        }
    }
}

// Kernel 2: 3x3 smooth-max pooling, 2 output rows x 8 px per thread via a
// 4-input-row sliding window: each loaded row's 10 exps are shared by up to
// 2 output rows (2.5 exps/px), loads/px halved vs round 4.
// grid = (16, 64), block 256 = 8 thread-rows x 32 col-segments.
// 1024 blocks x 4 waves = 4096 waves = 16 waves/CU (one residency round at
// ~80 VGPR). OOB taps: p=0 -> e=1 -> wt=kern, matching zero padding.
__global__ __launch_bounds__(256) void smoothmax_kernel(
        const float* __restrict__ x,
        const float* __restrict__ ak,
        float* __restrict__ out) {
    const int t   = threadIdx.x;
    const int b   = blockIdx.y;
    const int r0  = (blockIdx.x << 4) + ((t >> 5) << 1);  // even row 0..254
    const int c0  = (t & 31) << 3;                        // 0,8,...,248

    const float* akb = ak + b * 10;
    const float al2 = akb[0] * 1.44269504088896f;  // alpha * log2(e)
    float kern[9];
    #pragma unroll
    for (int i = 0; i < 9; ++i) kern[i] = akb[1 + i];

    const float* xb = x + ((size_t)b << 16);

    float num0[8], den0[8], num1[8], den1[8];
    #pragma unroll
    for (int i = 0; i < 8; ++i) {
        num0[i] = 0.f; den0[i] = 0.f;
        num1[i] = 0.f; den1[i] = 0.f;
    }

    // input rows r0-1 .. r0+2 ; row j feeds out-row0 (kern row j, j<3)
    // and out-row1 (kern row j-1, j>0)
    #pragma unroll
    for (int j = 0; j < 4; ++j) {
        const int rr = r0 - 1 + j;
        float p[10];
        if ((unsigned)rr < (unsigned)IMH) {
            const float* xr = xb + rr * IMW;
            const float4 v0 = *reinterpret_cast<const float4*>(xr + c0);
            const float4 v1 = *reinterpret_cast<const float4*>(xr + c0 + 4);
            p[0] = (c0 == 0)       ? 0.f : xr[c0 - 1];
            p[1] = v0.x; p[2] = v0.y; p[3] = v0.z; p[4] = v0.w;
            p[5] = v1.x; p[6] = v1.y; p[7] = v1.z; p[8] = v1.w;
            p[9] = (c0 == IMW - 8) ? 0.f : xr[c0 + 8];
        } else {
            #pragma unroll
            for (int q = 0; q < 10; ++q) p[q] = 0.f;
        }
        float e[10];
        #pragma unroll
        for (int q = 0; q < 10; ++q) e[q] = exp2f(al2 * p[q]);

        if (j < 3) {
            const int kr = 3 * j;
            #pragma unroll
            for (int i = 0; i < 8; ++i) {
                #pragma unroll
                for (int dx = 0; dx < 3; ++dx) {
                    const float wt = e[i + dx] * kern[kr + dx];
                    num0[i] = fmaf(p[i + dx], wt, num0[i]);
                    den0[i] += wt;
                }
            }
        }
        if (j > 0) {
            const int kr = 3 * (j - 1);
            #pragma unroll
            for (int i = 0; i < 8; ++i) {
                #pragma unroll
                for (int dx = 0; dx < 3; ++dx) {
                    const float wt = e[i + dx] * kern[kr + dx];
                    num1[i] = fmaf(p[i + dx], wt, num1[i]);
                    den1[i] += wt;
                }
            }
        }
    }

    float* ob = out + ((size_t)b << 16) + r0 * IMW + c0;
    float4 o0, o1;
    o0.x = num0[0] * __builtin_amdgcn_rcpf(den0[0]);
    o0.y = num0[1] * __builtin_amdgcn_rcpf(den0[1]);
    o0.z = num0[2] * __builtin_amdgcn_rcpf(den0[2]);
    o0.w = num0[3] * __builtin_amdgcn_rcpf(den0[3]);
    o1.x = num0[4] * __builtin_amdgcn_rcpf(den0[4]);
    o1.y = num0[5] * __builtin_amdgcn_rcpf(den0[5]);
    o1.z = num0[6] * __builtin_amdgcn_rcpf(den0[6]);
    o1.w = num0[7] * __builtin_amdgcn_rcpf(den0[7]);
    *reinterpret_cast<float4*>(ob)     = o0;
    *reinterpret_cast<float4*>(ob + 4) = o1;

    float4 p0, p1;
    p0.x = num1[0] * __builtin_amdgcn_rcpf(den1[0]);
    p0.y = num1[1] * __builtin_amdgcn_rcpf(den1[1]);
    p0.z = num1[2] * __builtin_amdgcn_rcpf(den1[2]);
    p0.w = num1[3] * __builtin_amdgcn_rcpf(den1[3]);
    p1.x = num1[4] * __builtin_amdgcn_rcpf(den1[4]);
    p1.y = num1[5] * __builtin_amdgcn_rcpf(den1[5]);
    p1.z = num1[6] * __builtin_amdgcn_rcpf(den1[6]);
    p1.w = num1[7] * __builtin_amdgcn_rcpf(den1[7]);
    *reinterpret_cast<float4*>(ob + IMW)     = p0;
    *reinterpret_cast<float4*>(ob + IMW + 4) = p1;
}

extern "C" void kernel_launch(void* const* d_in, const int* in_sizes, int n_in,
                              void* d_out, int out_size, void* d_ws, size_t ws_size,
                              hipStream_t stream) {
    const float* x        = (const float*)d_in[0];
    const float* features = (const float*)d_in[1];
    const float* W0       = (const float*)d_in[2];
    const float* b0       = (const float*)d_in[3];
    const float* W1       = (const float*)d_in[4];
    const float* b1       = (const float*)d_in[5];
    const float* W2       = (const float*)d_in[6];
    const float* b2       = (const float*)d_in[7];
    float* out = (float*)d_out;
    float* ak  = (float*)d_ws;  // BATCH*10 floats

    mlp_kernel<<<BATCH, 1024, 0, stream>>>(features, W0, b0, W1, b1, W2, b2, ak);
    smoothmax_kernel<<<dim3(16, BATCH), 256, 0, stream>>>(x, ak, out);
}

// Round 6
// 28.283 us; speedup vs baseline: 1.7605x; 1.0260x over previous
//
#include <hip/hip_runtime.h>

#define BATCH 64
#define IMH 256
#define IMW 256
#define CIN 512
#define NH 128

// Single fused kernel, 1024 blocks x 256 threads (4 waves) = 16 waves/CU.
// Each block: (A) redundantly computes the 10-wide MLP head for its batch
// (16 blocks/batch; weights are L2/L3-resident), (B) smooth-max-pools its
// 16 image rows with the round-5 2-rows/8-px sliding-window code.
//
// MLP layout: each wave computes 8 output rows AT ONCE: lane = (rsub, ksub)
// = (row-in-group, k-chunk). Per pass a lane loads one float4 of W and one
// float4 of the activation (LDS), giving 128B-coalesced weight reads and a
// conflict-free 8-address LDS broadcast; the reduction is 3 shfl_xor per
// 8 rows instead of 6 shuffles per row (round 3's serial-prefix killer).
__global__ __launch_bounds__(256) void fused_kernel(
        const float* __restrict__ x,
        const float* __restrict__ features,
        const float* __restrict__ W0, const float* __restrict__ b0,
        const float* __restrict__ W1, const float* __restrict__ b1,
        const float* __restrict__ W2, const float* __restrict__ b2,
        float* __restrict__ out) {
    const int t     = threadIdx.x;    // 0..255
    const int wave  = t >> 6;         // 0..3
    const int lane  = t & 63;
    const int batch = blockIdx.x >> 4;
    const int rgrp  = blockIdx.x & 15;

    const int rsub = lane >> 3;       // 0..7 row within 8-row group
    const int ksub = lane & 7;        // 0..7 k-chunk

    __shared__ float f[CIN];
    __shared__ float h0[NH];
    __shared__ float h1[NH];
    __shared__ float akl[10];

    // ---------------- phase A: MLP ----------------
    f[t]       = features[batch * CIN + t];
    f[t + 256] = features[batch * CIN + t + 256];
    __syncthreads();

    const float4* f4 = reinterpret_cast<const float4*>(f);

    // layer 0: rows wave*32 .. +31, 4 groups of 8 rows; dot over 512
    for (int g = 0; g < 4; ++g) {
        const int row = wave * 32 + g * 8 + rsub;
        const float4* w4 = reinterpret_cast<const float4*>(W0) + row * (CIN / 4) + ksub;
        float acc = 0.f;
        #pragma unroll
        for (int pass = 0; pass < 16; ++pass) {
            const float4 wv = w4[pass * 8];
            const float4 fv = f4[ksub + pass * 8];
            acc = fmaf(wv.x, fv.x, acc);
            acc = fmaf(wv.y, fv.y, acc);
            acc = fmaf(wv.z, fv.z, acc);
            acc = fmaf(wv.w, fv.w, acc);
        }
        acc += __shfl_xor(acc, 1);
        acc += __shfl_xor(acc, 2);
        acc += __shfl_xor(acc, 4);
        if (ksub == 0) h0[row] = fmaxf(acc + b0[row], 0.f);
    }
    __syncthreads();

    // layer 1: same structure, dot over 128
    const float4* h04 = reinterpret_cast<const float4*>(h0);
    for (int g = 0; g < 4; ++g) {
        const int row = wave * 32 + g * 8 + rsub;
        const float4* w4 = reinterpret_cast<const float4*>(W1) + row * (NH / 4) + ksub;
        float acc = 0.f;
        #pragma unroll
        for (int pass = 0; pass < 4; ++pass) {
            const float4 wv = w4[pass * 8];
            const float4 hv = h04[ksub + pass * 8];
            acc = fmaf(wv.x, hv.x, acc);
            acc = fmaf(wv.y, hv.y, acc);
            acc = fmaf(wv.z, hv.z, acc);
            acc = fmaf(wv.w, hv.w, acc);
        }
        acc += __shfl_xor(acc, 1);
        acc += __shfl_xor(acc, 2);
        acc += __shfl_xor(acc, 4);
        if (ksub == 0) h1[row] = fmaxf(acc + b1[row], 0.f);
    }
    __syncthreads();

    // head: 10 rows; wave 0 -> rows 0..7, wave 1 -> rows 8..9
    const int hrow = wave * 8 + rsub;
    if (wave < 2 && hrow < 10) {
        const float4* h14 = reinterpret_cast<const float4*>(h1);
        const float4* w4  = reinterpret_cast<const float4*>(W2) + hrow * (NH / 4) + ksub;
        float acc = 0.f;
        #pragma unroll
        for (int pass = 0; pass < 4; ++pass) {
            const float4 wv = w4[pass * 8];
            const float4 hv = h14[ksub + pass * 8];
            acc = fmaf(wv.x, hv.x, acc);
            acc = fmaf(wv.y, hv.y, acc);
            acc = fmaf(wv.z, hv.z, acc);
            acc = fmaf(wv.w, hv.w, acc);
        }
        acc += __shfl_xor(acc, 1);
        acc += __shfl_xor(acc, 2);
        acc += __shfl_xor(acc, 4);
        if (ksub == 0) {
            float beta = acc + b2[hrow];
            if (hrow == 0) {
                akl[0] = beta;                          // alpha
            } else {
                beta += (hrow == 5) ? 5.f : -5.f;       // identity bias (center +5)
                akl[hrow] = 1.f / (1.f + __expf(-beta)); // sigmoid
            }
        }
    }
    __syncthreads();

    const float al2 = akl[0] * 1.44269504088896f;  // alpha * log2(e)
    float kern[9];
    #pragma unroll
    for (int i = 0; i < 9; ++i) kern[i] = akl[1 + i];

    // ---------------- phase B: smooth-max pool 16 rows ----------------
    const int r0 = rgrp * 16 + ((t >> 5) << 1);    // even row, 0..254
    const int c0 = (t & 31) << 3;                  // 0,8,...,248

    const float* xb = x + ((size_t)batch << 16);

    float num0[8], den0[8], num1[8], den1[8];
    #pragma unroll
    for (int i = 0; i < 8; ++i) {
        num0[i] = 0.f; den0[i] = 0.f;
        num1[i] = 0.f; den1[i] = 0.f;
    }

    // input rows r0-1 .. r0+2; row j feeds out-row0 (kern row j, j<3)
    // and out-row1 (kern row j-1, j>0)
    #pragma unroll
    for (int j = 0; j < 4; ++j) {
        const int rr = r0 - 1 + j;
        float p[10];
        if ((unsigned)rr < (unsigned)IMH) {
            const float* xr = xb + rr * IMW;
            const float4 v0 = *reinterpret_cast<const float4*>(xr + c0);
            const float4 v1 = *reinterpret_cast<const float4*>(xr + c0 + 4);
            p[0] = (c0 == 0)       ? 0.f : xr[c0 - 1];
            p[1] = v0.x; p[2] = v0.y; p[3] = v0.z; p[4] = v0.w;
            p[5] = v1.x; p[6] = v1.y; p[7] = v1.z; p[8] = v1.w;
            p[9] = (c0 == IMW - 8) ? 0.f : xr[c0 + 8];
        } else {
            #pragma unroll
            for (int q = 0; q < 10; ++q) p[q] = 0.f;
        }
        float e[10];
        #pragma unroll
        for (int q = 0; q < 10; ++q) e[q] = exp2f(al2 * p[q]);

        if (j < 3) {
            const int kr = 3 * j;
            #pragma unroll
            for (int i = 0; i < 8; ++i) {
                #pragma unroll
                for (int dx = 0; dx < 3; ++dx) {
                    const float wt = e[i + dx] * kern[kr + dx];
                    num0[i] = fmaf(p[i + dx], wt, num0[i]);
                    den0[i] += wt;
                }
            }
        }
        if (j > 0) {
            const int kr = 3 * (j - 1);
            #pragma unroll
            for (int i = 0; i < 8; ++i) {
                #pragma unroll
                for (int dx = 0; dx < 3; ++dx) {
                    const float wt = e[i + dx] * kern[kr + dx];
                    num1[i] = fmaf(p[i + dx], wt, num1[i]);
                    den1[i] += wt;
                }
            }
        }
    }

    float* ob = out + ((size_t)batch << 16) + r0 * IMW + c0;
    float4 o0, o1;
    o0.x = num0[0] * __builtin_amdgcn_rcpf(den0[0]);
    o0.y = num0[1] * __builtin_amdgcn_rcpf(den0[1]);
    o0.z = num0[2] * __builtin_amdgcn_rcpf(den0[2]);
    o0.w = num0[3] * __builtin_amdgcn_rcpf(den0[3]);
    o1.x = num0[4] * __builtin_amdgcn_rcpf(den0[4]);
    o1.y = num0[5] * __builtin_amdgcn_rcpf(den0[5]);
    o1.z = num0[6] * __builtin_amdgcn_rcpf(den0[6]);
    o1.w = num0[7] * __builtin_amdgcn_rcpf(den0[7]);
    *reinterpret_cast<float4*>(ob)     = o0;
    *reinterpret_cast<float4*>(ob + 4) = o1;

    float4 p0, p1;
    p0.x = num1[0] * __builtin_amdgcn_rcpf(den1[0]);
    p0.y = num1[1] * __builtin_amdgcn_rcpf(den1[1]);
    p0.z = num1[2] * __builtin_amdgcn_rcpf(den1[2]);
    p0.w = num1[3] * __builtin_amdgcn_rcpf(den1[3]);
    p1.x = num1[4] * __builtin_amdgcn_rcpf(den1[4]);
    p1.y = num1[5] * __builtin_amdgcn_rcpf(den1[5]);
    p1.z = num1[6] * __builtin_amdgcn_rcpf(den1[6]);
    p1.w = num1[7] * __builtin_amdgcn_rcpf(den1[7]);
    *reinterpret_cast<float4*>(ob + IMW)     = p0;
    *reinterpret_cast<float4*>(ob + IMW + 4) = p1;
}

extern "C" void kernel_launch(void* const* d_in, const int* in_sizes, int n_in,
                              void* d_out, int out_size, void* d_ws, size_t ws_size,
                              hipStream_t stream) {
    const float* x        = (const float*)d_in[0];
    const float* features = (const float*)d_in[1];
    const float* W0       = (const float*)d_in[2];
    const float* b0       = (const float*)d_in[3];
    const float* W1       = (const float*)d_in[4];
    const float* b1       = (const float*)d_in[5];
    const float* W2       = (const float*)d_in[6];
    const float* b2       = (const float*)d_in[7];
    float* out = (float*)d_out;

    fused_kernel<<<BATCH * 16, 256, 0, stream>>>(
        x, features, W0, b0, W1, b1, W2, b2, out);
}

// Round 7
// 19.720 us; speedup vs baseline: 2.5250x; 1.4342x over previous
//
#include <hip/hip_runtime.h>

#define BATCH 64
#define IMH 256
#define IMW 256
#define CIN 512
#define NH 128
#define BPB 4                 // blocks per batch
#define ROWS_PB (IMH / BPB)   // 64 image rows per block

// Single fused kernel, 256 blocks x 1024 threads (16 waves) = 16 waves/CU.
// Phase A: each block redundantly computes the 10-wide MLP head for its
// batch (4 blocks/batch -> 83 MB aggregate L2 weight traffic, 4x less than
// round 6's 16 blocks/batch). Each of the 16 waves computes 8 MLP rows at
// once: lane=(rsub,ksub), float4 coalesced weight loads, 3 shfl_xor reduce.
// Phase B: block pools its 64 image rows, 2 output rows x 8 px per thread
// via a 4-input-row sliding window (2.5 exps/px).
__global__ __launch_bounds__(1024) void fused_kernel(
        const float* __restrict__ x,
        const float* __restrict__ features,
        const float* __restrict__ W0, const float* __restrict__ b0,
        const float* __restrict__ W1, const float* __restrict__ b1,
        const float* __restrict__ W2, const float* __restrict__ b2,
        float* __restrict__ out) {
    const int t     = threadIdx.x;    // 0..1023
    const int wave  = t >> 6;         // 0..15
    const int lane  = t & 63;
    const int batch = blockIdx.x >> 2;
    const int rgrp  = blockIdx.x & 3;

    const int rsub = lane >> 3;       // 0..7 row within 8-row group
    const int ksub = lane & 7;        // 0..7 k-chunk

    __shared__ float f[CIN];
    __shared__ float h0[NH];
    __shared__ float h1[NH];
    __shared__ float akl[10];

    // ---------------- phase A: MLP ----------------
    if (t < CIN) f[t] = features[batch * CIN + t];
    __syncthreads();

    const float4* f4 = reinterpret_cast<const float4*>(f);

    // layer 0: wave w owns rows 8w..8w+7; dot over 512 (16 float4 passes)
    {
        const int row = wave * 8 + rsub;
        const float4* w4 = reinterpret_cast<const float4*>(W0) + row * (CIN / 4) + ksub;
        float acc = 0.f;
        #pragma unroll
        for (int pass = 0; pass < 16; ++pass) {
            const float4 wv = w4[pass * 8];
            const float4 fv = f4[ksub + pass * 8];
            acc = fmaf(wv.x, fv.x, acc);
            acc = fmaf(wv.y, fv.y, acc);
            acc = fmaf(wv.z, fv.z, acc);
            acc = fmaf(wv.w, fv.w, acc);
        }
        acc += __shfl_xor(acc, 1);
        acc += __shfl_xor(acc, 2);
        acc += __shfl_xor(acc, 4);
        if (ksub == 0) h0[row] = fmaxf(acc + b0[row], 0.f);
    }
    __syncthreads();

    // layer 1: dot over 128 (4 float4 passes)
    const float4* h04 = reinterpret_cast<const float4*>(h0);
    {
        const int row = wave * 8 + rsub;
        const float4* w4 = reinterpret_cast<const float4*>(W1) + row * (NH / 4) + ksub;
        float acc = 0.f;
        #pragma unroll
        for (int pass = 0; pass < 4; ++pass) {
            const float4 wv = w4[pass * 8];
            const float4 hv = h04[ksub + pass * 8];
            acc = fmaf(wv.x, hv.x, acc);
            acc = fmaf(wv.y, hv.y, acc);
            acc = fmaf(wv.z, hv.z, acc);
            acc = fmaf(wv.w, hv.w, acc);
        }
        acc += __shfl_xor(acc, 1);
        acc += __shfl_xor(acc, 2);
        acc += __shfl_xor(acc, 4);
        if (ksub == 0) h1[row] = fmaxf(acc + b1[row], 0.f);
    }
    __syncthreads();

    // head: 10 rows; wave 0 -> rows 0..7, wave 1 -> rows 8..9
    const int hrow = wave * 8 + rsub;
    if (wave < 2 && hrow < 10) {
        const float4* h14 = reinterpret_cast<const float4*>(h1);
        const float4* w4  = reinterpret_cast<const float4*>(W2) + hrow * (NH / 4) + ksub;
        float acc = 0.f;
        #pragma unroll
        for (int pass = 0; pass < 4; ++pass) {
            const float4 wv = w4[pass * 8];
            const float4 hv = h14[ksub + pass * 8];
            acc = fmaf(wv.x, hv.x, acc);
            acc = fmaf(wv.y, hv.y, acc);
            acc = fmaf(wv.z, hv.z, acc);
            acc = fmaf(wv.w, hv.w, acc);
        }
        acc += __shfl_xor(acc, 1);
        acc += __shfl_xor(acc, 2);
        acc += __shfl_xor(acc, 4);
        if (ksub == 0) {
            float beta = acc + b2[hrow];
            if (hrow == 0) {
                akl[0] = beta;                           // alpha
            } else {
                beta += (hrow == 5) ? 5.f : -5.f;        // identity bias (center +5)
                akl[hrow] = 1.f / (1.f + __expf(-beta)); // sigmoid
            }
        }
    }
    __syncthreads();

    const float al2 = akl[0] * 1.44269504088896f;  // alpha * log2(e)
    float kern[9];
    #pragma unroll
    for (int i = 0; i < 9; ++i) kern[i] = akl[1 + i];

    // ---------------- phase B: smooth-max pool 64 rows ----------------
    // 1024 threads = 32 thread-rows x 32 col-segments; 2 rows x 8 px each.
    const int r0 = rgrp * ROWS_PB + ((t >> 5) << 1);   // even row
    const int c0 = (t & 31) << 3;                      // 0,8,...,248

    const float* xb = x + ((size_t)batch << 16);

    float num0[8], den0[8], num1[8], den1[8];
    #pragma unroll
    for (int i = 0; i < 8; ++i) {
        num0[i] = 0.f; den0[i] = 0.f;
        num1[i] = 0.f; den1[i] = 0.f;
    }

    // input rows r0-1 .. r0+2; row j feeds out-row0 (kern row j, j<3)
    // and out-row1 (kern row j-1, j>0)
    #pragma unroll
    for (int j = 0; j < 4; ++j) {
        const int rr = r0 - 1 + j;
        float p[10];
        if ((unsigned)rr < (unsigned)IMH) {
            const float* xr = xb + rr * IMW;
            const float4 v0 = *reinterpret_cast<const float4*>(xr + c0);
            const float4 v1 = *reinterpret_cast<const float4*>(xr + c0 + 4);
            p[0] = (c0 == 0)       ? 0.f : xr[c0 - 1];
            p[1] = v0.x; p[2] = v0.y; p[3] = v0.z; p[4] = v0.w;
            p[5] = v1.x; p[6] = v1.y; p[7] = v1.z; p[8] = v1.w;
            p[9] = (c0 == IMW - 8) ? 0.f : xr[c0 + 8];
        } else {
            #pragma unroll
            for (int q = 0; q < 10; ++q) p[q] = 0.f;
        }
        float e[10];
        #pragma unroll
        for (int q = 0; q < 10; ++q) e[q] = exp2f(al2 * p[q]);

        if (j < 3) {
            const int kr = 3 * j;
            #pragma unroll
            for (int i = 0; i < 8; ++i) {
                #pragma unroll
                for (int dx = 0; dx < 3; ++dx) {
                    const float wt = e[i + dx] * kern[kr + dx];
                    num0[i] = fmaf(p[i + dx], wt, num0[i]);
                    den0[i] += wt;
                }
            }
        }
        if (j > 0) {
            const int kr = 3 * (j - 1);
            #pragma unroll
            for (int i = 0; i < 8; ++i) {
                #pragma unroll
                for (int dx = 0; dx < 3; ++dx) {
                    const float wt = e[i + dx] * kern[kr + dx];
                    num1[i] = fmaf(p[i + dx], wt, num1[i]);
                    den1[i] += wt;
                }
            }
        }
    }

    float* ob = out + ((size_t)batch << 16) + r0 * IMW + c0;
    float4 o0, o1;
    o0.x = num0[0] * __builtin_amdgcn_rcpf(den0[0]);
    o0.y = num0[1] * __builtin_amdgcn_rcpf(den0[1]);
    o0.z = num0[2] * __builtin_amdgcn_rcpf(den0[2]);
    o0.w = num0[3] * __builtin_amdgcn_rcpf(den0[3]);
    o1.x = num0[4] * __builtin_amdgcn_rcpf(den0[4]);
    o1.y = num0[5] * __builtin_amdgcn_rcpf(den0[5]);
    o1.z = num0[6] * __builtin_amdgcn_rcpf(den0[6]);
    o1.w = num0[7] * __builtin_amdgcn_rcpf(den0[7]);
    *reinterpret_cast<float4*>(ob)     = o0;
    *reinterpret_cast<float4*>(ob + 4) = o1;

    float4 p0, p1;
    p0.x = num1[0] * __builtin_amdgcn_rcpf(den1[0]);
    p0.y = num1[1] * __builtin_amdgcn_rcpf(den1[1]);
    p0.z = num1[2] * __builtin_amdgcn_rcpf(den1[2]);
    p0.w = num1[3] * __builtin_amdgcn_rcpf(den1[3]);
    p1.x = num1[4] * __builtin_amdgcn_rcpf(den1[4]);
    p1.y = num1[5] * __builtin_amdgcn_rcpf(den1[5]);
    p1.z = num1[6] * __builtin_amdgcn_rcpf(den1[6]);
    p1.w = num1[7] * __builtin_amdgcn_rcpf(den1[7]);
    *reinterpret_cast<float4*>(ob + IMW)     = p0;
    *reinterpret_cast<float4*>(ob + IMW + 4) = p1;
}

extern "C" void kernel_launch(void* const* d_in, const int* in_sizes, int n_in,
                              void* d_out, int out_size, void* d_ws, size_t ws_size,
                              hipStream_t stream) {
    const float* x        = (const float*)d_in[0];
    const float* features = (const float*)d_in[1];
    const float* W0       = (const float*)d_in[2];
    const float* b0       = (const float*)d_in[3];
    const float* W1       = (const float*)d_in[4];
    const float* b1       = (const float*)d_in[5];
    const float* W2       = (const float*)d_in[6];
    const float* b2       = (const float*)d_in[7];
    float* out = (float*)d_out;

    fused_kernel<<<BATCH * BPB, 1024, 0, stream>>>(
        x, features, W0, b0, W1, b1, W2, b2, out);
}